// Round 1
// baseline (86.116 us; speedup 1.0000x reference)
//
#include <hip/hip_runtime.h>
#include <math.h>

// Problem constants (from reference / setup_inputs)
#define N_ROIS   32
#define N_CAT    (N_ROIS * 9)      // 288 cat_rois rows
#define C_FEAT   256
#define H_FEAT   40
#define W_FEAT   40
#define P_FEAT   (H_FEAT * W_FEAT) // 1600 pixels
#define PH       7
#define PW       7
#define SCALE    0.0625f
#define MIN_SIZE 16.0f
#define CELLS    (PH * PW)                 // 49
#define POOL_PER_BOX (C_FEAT * CELLS)      // 12544
#define OUT_POOL_ELEMS ((size_t)N_CAT * POOL_PER_BOX)  // 3,612,672

#define N_TRANS_BLOCKS (P_FEAT / 32 * (C_FEAT / 32))   // 50*8 = 400
#define WIN 14   // static row window: bsw<=2 -> box spans <=14 feature cols

// Pool grid geometry: block = (box, channel-half). 576 blocks, 512 threads.
#define CH_HALF   128                       // channels per block
#define POOL_BLKS (N_CAT * 2)               // 576 (== 8 * 72, XCD-bijective)
#define HALF_ELEMS (CH_HALF * CELLS)        // 6272 floats = 25,088 B (16B-mult)

// ---------------------------------------------------------------------------
// Kernel 0 (fused prep): blocks 0..399 transpose features (C,P)->(P,C);
// block 400 computes context anchors + IoU labeling -> cat_rois (288x5).
// (UNCHANGED from previous round — proven correct, ~model 5us.)
// ---------------------------------------------------------------------------
__global__ void prep_kernel(const float* __restrict__ f,
                            const float* __restrict__ rois,
                            const int* __restrict__ hh_p,
                            const int* __restrict__ hw_p,
                            float* __restrict__ ft,
                            float* __restrict__ cat_out,
                            int use_transpose) {
    __shared__ float tile[32][33];   // transpose tile (+1 pad)
    __shared__ float R[N_ROIS * 5];  // rois stage for context half
    const int bid = blockIdx.x;
    const int tid = threadIdx.x;

    if (bid < N_TRANS_BLOCKS) {
        if (!use_transpose) return;
        const int pt = (bid % (P_FEAT / 32)) * 32;
        const int ct = (bid / (P_FEAT / 32)) * 32;
        const int lx = tid & 31;
        const int ly = tid >> 5;     // 0..7
        #pragma unroll
        for (int i = 0; i < 32; i += 8)
            tile[ly + i][lx] = f[(ct + ly + i) * P_FEAT + (pt + lx)];
        __syncthreads();
        #pragma unroll
        for (int i = 0; i < 32; i += 8)
            ft[(pt + ly + i) * C_FEAT + (ct + lx)] = tile[lx][ly + i];
        return;
    }

    // ---- context-anchor half (one block, 256 threads) ----
    if (tid < N_ROIS * 5) R[tid] = rois[tid];
    __syncthreads();

    const float hh = (float)(*hh_p);
    const float hw = (float)(*hw_p);

    const int g = tid;               // 0..255 -> gt box
    const int n = g >> 3;
    const int j = g & 7;
    const int m = (j < 4) ? j : j + 1;   // skip center of 3x3
    const int r  = m / 3;
    const int cc = m % 3;

    const float x1 = R[n * 5 + 1], y1 = R[n * 5 + 2];
    const float x2 = R[n * 5 + 3], y2 = R[n * 5 + 4];
    const float w = x2 - x1, h = y2 - y1;

    const float cx = x1 + w * ((float)cc - 0.5f);
    const float cy = y1 + h * ((float)r  - 0.5f);
    float bx1 = cx - w * 0.25f;
    float by1 = cy - h * 0.25f;
    float bx2 = cx + w * 0.25f;
    float by2 = cy + h * 0.25f;
    const float bw = bx2 - bx1 + 1.0f;
    const float bh = by2 - by1 + 1.0f;
    const bool invalid = (bx1 < 0.0f) || (by1 < 0.0f) ||
                         (bx2 >= hw) || (by2 >= hh) ||
                         (bw < MIN_SIZE) || (bh < MIN_SIZE);
    if (invalid) { bx1 = x1; by1 = y1; bx2 = x2; by2 = y2; }

    const float gw = bx2 - bx1 + 1.0f;
    const float gh = by2 - by1 + 1.0f;
    const float garea = gw * gh;
    const bool gdeg = (gw == 1.0f) && (gh == 1.0f);

    float best_ov = -INFINITY;
    int best = 0;
    for (int a = 0; a < N_ROIS; ++a) {
        const float ax1 = R[a * 5 + 1], ay1 = R[a * 5 + 2];
        const float ax2 = R[a * 5 + 3], ay2 = R[a * 5 + 4];
        const float aw = ax2 - ax1 + 1.0f, ah = ay2 - ay1 + 1.0f;
        float iw = fminf(ax2, bx2) - fmaxf(ax1, bx1) + 1.0f;
        float ih = fminf(ay2, by2) - fmaxf(ay1, by1) + 1.0f;
        iw = fmaxf(iw, 0.0f);
        ih = fmaxf(ih, 0.0f);
        const float inter = iw * ih;
        float ov = inter / (aw * ah + garea - inter);
        if (gdeg) ov = 0.0f;
        if (aw == 1.0f && ah == 1.0f) ov = -1.0f;
        if (ov > best_ov) { best_ov = ov; best = a; }
    }

    bool label = (best_ov >= 0.3f);
    const float w_cell = bx2 - bx1;
    const float h_cell = by2 - by1;
    const float rw = label ? (R[best * 5 + 3] - R[best * 5 + 1]) : 0.0f;
    const float rh = label ? (R[best * 5 + 4] - R[best * 5 + 2]) : 0.0f;
    label = label &&
            !(fmaxf(rw, rh) >= fmaxf(w_cell, h_cell)) &&
            !(fminf(rw, rh) < fminf(w_cell, h_cell) / 3.0f);
    if (label) {
        bx1 = R[best * 5 + 1]; by1 = R[best * 5 + 2];
        bx2 = R[best * 5 + 3]; by2 = R[best * 5 + 4];
    }

    float* row = cat_out + (size_t)(n * 9 + 1 + j) * 5;
    row[0] = 0.0f;
    row[1] = bx1; row[2] = by1; row[3] = bx2; row[4] = by2;
    if (j == 0) {
        float* rr = cat_out + (size_t)(n * 9) * 5;
        #pragma unroll
        for (int t = 0; t < 5; ++t) rr[t] = R[n * 5 + t];
    }
}

// ---------------------------------------------------------------------------
// Kernel 1 (NEW): box-major RoIPool with LDS-staged, fully-coalesced stores.
//
// Grid: 576 blocks = (box b, channel-half). 512 threads = (128 channels x
// 4 pooled-row groups iq; iq owns rows {iq, iq+4}). Inner loop per row is
// IDENTICAL to the proven (i,b)-block kernel: 14 batched independent window
// loads (one vmcnt group), branch-free predicated maxes, kmax=2j+2 pruning.
//
// Why regroup: the old layout stored 7 floats/thread at 196B stride ->
// every wave store touched 64 distinct lines -> 3.6M L1->L2 write
// transactions for 14.5MB of payload (16x amplification, ~1 line/cy TA
// serialization per CU). Here each block's output (128ch x 49 cells =
// 25,088B) is CONTIGUOUS in global memory, so we stage it in LDS
// (stride-49 float writes: lane*49 % 32 = lane*17 % 32 -> odd-stride bank
// permutation, conflict-free) and drain with dense float4 stores: 226K
// write transactions total.
//
// XCD swizzle (chunked-bijective, 576 = 8*72): dispatched block d -> XCD
// d%8 (round-robin heuristic); s = (d%8)*72 + d/8 gives XCD k the boxes
// [k*36, (k+1)*36) = 4 parent rois + their 8 context boxes each, which
// overlap spatially -> ft row reads stay L2-local per XCD.
// ---------------------------------------------------------------------------
__global__ __launch_bounds__(512, 4) void
pool_box_kernel(const float* __restrict__ feat,
                const float* __restrict__ cat_rois,
                float* __restrict__ out) {
    __shared__ __align__(16) float obuf[HALF_ELEMS];   // 25,088 B

    const int s     = (blockIdx.x & 7) * (POOL_BLKS / 8) + (blockIdx.x >> 3);
    const int b     = s >> 1;          // box 0..287
    const int chalf = s & 1;           // channel half 0/1
    const int tid   = threadIdx.x;
    const int cl    = tid & (CH_HALF - 1);        // local channel 0..127
    const int c     = chalf * CH_HALF + cl;       // global channel
    const int iq    = tid >> 7;                   // row group 0..3

    const float* cr = cat_rois + (size_t)b * 5;
    const float x1 = cr[1], y1 = cr[2], x2 = cr[3], y2 = cr[4];
    // jnp.round = round-half-to-even = rintf (default rounding mode)
    const float sw = rintf(x1 * SCALE);
    const float sh = rintf(y1 * SCALE);
    const float ew = rintf(x2 * SCALE);
    const float eh = rintf(y2 * SCALE);
    const float bsh = fmaxf(eh - sh + 1.0f, 1.0f) * (1.0f / (float)PH);
    const float bsw = fmaxf(ew - sw + 1.0f, 1.0f) * (1.0f / (float)PW);

    int ws[PW], we[PW];
    #pragma unroll
    for (int j = 0; j < PW; ++j) {
        ws[j] = (int)fminf(fmaxf(floorf((float)j * bsw) + sw, 0.0f), (float)W_FEAT);
        we[j] = (int)fminf(fmaxf(ceilf((float)(j + 1) * bsw) + sw, 0.0f), (float)W_FEAT);
    }

    const int xs = ws[0];              // window start (>=0 for this data)
    const bool narrow = (bsw <= 2.0f); // guarantees span<=14 and we[j]<=xs+2j+2

    #pragma unroll
    for (int ii = 0; ii < 2; ++ii) {
        const int i = iq + ii * 4;     // iq=0..2 own {iq, iq+4}; iq=3 owns {3}
        if (i >= PH) break;            // uniform per wave (iq = tid>>7)

        const int hs = (int)fminf(fmaxf(floorf((float)i * bsh) + sh, 0.0f), (float)H_FEAT);
        const int he = (int)fminf(fmaxf(ceilf((float)(i + 1) * bsh) + sh, 0.0f), (float)H_FEAT);

        float mx[PW];
        #pragma unroll
        for (int j = 0; j < PW; ++j) mx[j] = -1e30f;

        if (narrow) {
            for (int y = hs; y < he; ++y) {
                const float* fr = feat + (size_t)(y * W_FEAT) * C_FEAT + c;
                // 14 independent batched loads (one vmcnt group, no serial chains)
                float win[WIN];
                #pragma unroll
                for (int k = 0; k < WIN; ++k) {
                    int x = xs + k;
                    x = (x < W_FEAT - 1) ? x : (W_FEAT - 1);  // clamp addr; unused if OOB
                    win[k] = fr[(size_t)x * C_FEAT];
                }
                #pragma unroll
                for (int j = 0; j < PW; ++j) {
                    const int lo = ws[j], hi = we[j];
                    const int kmax = (2 * j + 2 < WIN) ? (2 * j + 2) : WIN;
                    #pragma unroll
                    for (int k = 0; k < kmax; ++k) {
                        const int x = xs + k;
                        const bool in = (x >= lo) & (x < hi);
                        const float t = fmaxf(mx[j], win[k]);
                        mx[j] = in ? t : mx[j];      // v_cndmask, no branch
                    }
                }
            }
        } else {
            // general fallback (not taken for this data): dynamic loops
            for (int y = hs; y < he; ++y) {
                const float* fr = feat + (size_t)(y * W_FEAT) * C_FEAT + c;
                #pragma unroll
                for (int j = 0; j < PW; ++j)
                    for (int x = ws[j]; x < we[j]; ++x)
                        mx[j] = fmaxf(mx[j], fr[(size_t)x * C_FEAT]);
            }
        }

        const bool rowv = (he > hs);
        float* orow = obuf + cl * CELLS + i * PW;   // stride-49: bank-conflict-free
        #pragma unroll
        for (int j = 0; j < PW; ++j)
            orow[j] = (rowv && (we[j] > ws[j])) ? mx[j] : 0.0f;
    }

    __syncthreads();

    // Dense, fully-coalesced drain: 1568 float4 over 512 threads.
    const float4* src = reinterpret_cast<const float4*>(obuf);
    float4* dst = reinterpret_cast<float4*>(out + (size_t)b * POOL_PER_BOX
                                                + (size_t)chalf * HALF_ELEMS);
    for (int e = tid; e < HALF_ELEMS / 4; e += 512)
        dst[e] = src[e];
}

// fallback pool (untransposed layout) — only used if ws too small
__global__ __launch_bounds__(256) void
roi_pool_kernel_nchw(const float* __restrict__ feat,
                     const float* __restrict__ cat_rois,
                     float* __restrict__ out) {
    const int i = blockIdx.x / N_CAT;
    const int b = blockIdx.x % N_CAT;
    const int c = threadIdx.x;

    const float* cr = cat_rois + (size_t)b * 5;
    const float sw = rintf(cr[1] * SCALE);
    const float sh = rintf(cr[2] * SCALE);
    const float ew = rintf(cr[3] * SCALE);
    const float eh = rintf(cr[4] * SCALE);
    const float bsh = fmaxf(eh - sh + 1.0f, 1.0f) * (1.0f / (float)PH);
    const float bsw = fmaxf(ew - sw + 1.0f, 1.0f) * (1.0f / (float)PW);

    const int hs = (int)fminf(fmaxf(floorf((float)i * bsh) + sh, 0.0f), (float)H_FEAT);
    const int he = (int)fminf(fmaxf(ceilf((float)(i + 1) * bsh) + sh, 0.0f), (float)H_FEAT);
    int ws[PW], we[PW];
    #pragma unroll
    for (int j = 0; j < PW; ++j) {
        ws[j] = (int)fminf(fmaxf(floorf((float)j * bsw) + sw, 0.0f), (float)W_FEAT);
        we[j] = (int)fminf(fmaxf(ceilf((float)(j + 1) * bsw) + sw, 0.0f), (float)W_FEAT);
    }
    float mx[PW];
    #pragma unroll
    for (int j = 0; j < PW; ++j) mx[j] = -1e30f;
    for (int y = hs; y < he; ++y) {
        const float* fr = feat + (size_t)c * P_FEAT + y * W_FEAT;
        #pragma unroll
        for (int j = 0; j < PW; ++j)
            for (int x = ws[j]; x < we[j]; ++x)
                mx[j] = fmaxf(mx[j], fr[x]);
    }
    const bool rowv = (he > hs);
    float* ob = out + (size_t)b * POOL_PER_BOX + (size_t)c * CELLS + i * PW;
    #pragma unroll
    for (int j = 0; j < PW; ++j)
        ob[j] = (rowv && (we[j] > ws[j])) ? mx[j] : 0.0f;
}

// ---------------------------------------------------------------------------
extern "C" void kernel_launch(void* const* d_in, const int* in_sizes, int n_in,
                              void* d_out, int out_size, void* d_ws, size_t ws_size,
                              hipStream_t stream) {
    const float* features = (const float*)d_in[0];   // (1,256,40,40)
    const float* rois     = (const float*)d_in[1];   // (32,5)
    const int*   hh_p     = (const int*)d_in[2];
    const int*   hw_p     = (const int*)d_in[3];

    float* out      = (float*)d_out;
    float* cat_out  = out + OUT_POOL_ELEMS;          // (288,5) tail of d_out
    float* ft       = (float*)d_ws;                  // transposed features

    const size_t ft_bytes = (size_t)C_FEAT * P_FEAT * sizeof(float);
    const int use_transpose = (ws_size >= ft_bytes) ? 1 : 0;

    hipLaunchKernelGGL(prep_kernel, dim3(N_TRANS_BLOCKS + 1), dim3(256), 0, stream,
                       features, rois, hh_p, hw_p, ft, cat_out, use_transpose);

    if (use_transpose) {
        hipLaunchKernelGGL(pool_box_kernel, dim3(POOL_BLKS), dim3(512), 0, stream,
                           ft, cat_out, out);
    } else {
        hipLaunchKernelGGL(roi_pool_kernel_nchw, dim3(PH * N_CAT), dim3(C_FEAT), 0, stream,
                           features, cat_out, out);
    }
}